// Round 2
// baseline (14255.908 us; speedup 1.0000x reference)
//
#include <hip/hip_runtime.h>
#include <math.h>

#define BB 16
#define LL 64
#define TT 63          // L-1 steps
#define HH 512
#define AA 32          // ATTN window
#define VV 32000
#define NCHUNK 250     // V chunks for big matmul
#define CHW 128        // cols per chunk (250*128 = 32000)
#define PAD_TOK 1
#define SOS_TOK 2
#define HSROW 96       // A + L rows in hs_buf
#define FLTMAX 3.402823466e38f

__device__ __forceinline__ float sigm(float x){ return 1.0f/(1.0f + __expf(-x)); }

// ---------------- prologue: xwpre[t][b][:] = b_ctx + emb[tok(t,b)] @ W_ctx[0:512] ----------------
__global__ void k_pre(const int* __restrict__ s, const float* __restrict__ emb,
                      const float* __restrict__ Wctx, const float* __restrict__ bctx,
                      float* __restrict__ xwpre)
{
    int t = blockIdx.x / BB, b = blockIdx.x % BB;
    int tok = (t == 0) ? SOS_TOK : s[b*LL + (t-1)];
    const float* x = emb + (size_t)tok * HH;
    __shared__ float xs[HH];
    for (int k = threadIdx.x; k < HH; k += blockDim.x) xs[k] = x[k];
    __syncthreads();
    for (int j = threadIdx.x; j < HH; j += blockDim.x) {
        float acc = bctx[j];
        for (int k = 0; k < HH; k += 4) {
            float4 hv = *reinterpret_cast<const float4*>(&xs[k]);
            acc = fmaf(hv.x, Wctx[(k+0)*HH+j], acc);
            acc = fmaf(hv.y, Wctx[(k+1)*HH+j], acc);
            acc = fmaf(hv.z, Wctx[(k+2)*HH+j], acc);
            acc = fmaf(hv.w, Wctx[(k+3)*HH+j], acc);
        }
        xwpre[((size_t)t*BB + b)*HH + j] = acc;
    }
}

// ---------------- step-finish: replicate fp32 log_softmax + s*logp quantization ----------------
// Called by all 512 threads of a block handling batch row b, for step tp.
// pred = argmax_col fl32(s * fl32(fl32(x - gmax) - logS)), lowest-index tie-break (np.argmax).
__device__ void finish_step(int tp, int b, int tid,
                            const int* __restrict__ s,
                            const float* __restrict__ lb,
                            const float* __restrict__ pmax,
                            const float* __restrict__ spart,
                            const float* __restrict__ bsw,
                            float* __restrict__ nll, float* __restrict__ out,
                            float* cv, int* ci, double* sdd, float* extra)
{
    // gmax over 250 chunk maxes
    float v = -FLTMAX;
    if (tid < NCHUNK) v = pmax[tid*BB + b];
    cv[tid] = v; __syncthreads();
    for (int sft = 256; sft >= 1; sft >>= 1) {
        if (tid < sft) cv[tid] = fmaxf(cv[tid], cv[tid+sft]);
        __syncthreads();
    }
    float gmax = cv[0];
    __syncthreads();

    // pass A: S = sum exp(fl32(x - gmax)), fp64 Taylor (|u| small; bias-free)
    const float* Lb = lb + (size_t)b*VV;
    double sd = 0.0;
    for (int col = tid; col < VV; col += 512) {
        float d1 = Lb[col] - gmax;
        double u = (double)d1, e;
        if (u < -0.25) {
            e = exp(u);
        } else {
            e = 1.0 + u*(1.0/7.0);
            e = 1.0 + u*e*(1.0/6.0);
            e = 1.0 + u*e*(1.0/5.0);
            e = 1.0 + u*e*(1.0/4.0);
            e = 1.0 + u*e*(1.0/3.0);
            e = 1.0 + u*e*(1.0/2.0);
            e = 1.0 + u*e;
        }
        sd += e;
    }
    sdd[tid] = sd; __syncthreads();
    for (int sft = 256; sft >= 1; sft >>= 1) {
        if (tid < sft) sdd[tid] += sdd[tid+sft];
        __syncthreads();
    }
    float logS = logf((float)sdd[0]);

    // switch s = sigmoid(z), precise expf (replicates np's 1/(1+exp(-z)))
    float z = bsw[0];
    #pragma unroll
    for (int i2 = 0; i2 < 8; i2++) z += spart[b*8 + i2];
    float sF = 1.0f/(1.0f + expf(-z));
    __syncthreads();

    // pass B: quantized argmax + target capture
    int tg = s[b*LL + tp + 1];
    float best = -FLTMAX; int bidx = 0x7fffffff;
    for (int col = tid; col < VV; col += 512) {
        float d1 = Lb[col] - gmax;
        float d2 = d1 - logS;
        float pq = sF * d2;
        if (pq > best) { best = pq; bidx = col; }
        if (col == tg) extra[0] = pq;
    }
    cv[tid] = best; ci[tid] = bidx; __syncthreads();
    for (int sft = 256; sft >= 1; sft >>= 1) {
        if (tid < sft) {
            float v2 = cv[tid+sft]; int i2 = ci[tid+sft];
            if (v2 > cv[tid] || (v2 == cv[tid] && i2 < ci[tid])) { cv[tid] = v2; ci[tid] = i2; }
        }
        __syncthreads();
    }
    if (tid == 0) {
        out[1 + b*TT + tp] = (float)ci[0];
        nll[tp*BB + b] = (tg != PAD_TOK) ? -extra[0] : 0.f;
    }
    __syncthreads();
}

// ---------------- per-step kernel 1: finish prev step + attention + hid ----------------
__global__ __launch_bounds__(512) void k_attn(
    int t, const int* __restrict__ s,
    const float* __restrict__ Whid, const float* __restrict__ bhid,
    const float* __restrict__ vw, const float* __restrict__ vb,
    const float* __restrict__ Wctx, const float* __restrict__ xwpre,
    const float* __restrict__ hs, float* __restrict__ hidg,
    const float* __restrict__ lb, const float* __restrict__ pmax,
    const float* __restrict__ spart, const float* __restrict__ bsw,
    float* __restrict__ nll, float* __restrict__ out)
{
    int b = blockIdx.x, tid = threadIdx.x;
    __shared__ float hsh[HH], qs[HH], ctxs[HH];
    __shared__ float sc[AA], at[AA];
    __shared__ float cv[512];
    __shared__ int   ci[512];
    __shared__ double sdd[512];
    __shared__ float extra[2];

    // ---- phase 0: finish step t-1 ----
    if (t > 0) {
        finish_step(t-1, b, tid, s, lb, pmax, spart, bsw, nll, out, cv, ci, sdd, extra);
    }

    // ---- phase 1: load h_prev (hs row A+t-1; t=0 -> row 31 = zeros) ----
    const float* hp = hs + ((size_t)b*HSROW + (AA + t - 1))*HH;
    for (int k = tid; k < HH; k += 512) hsh[k] = hp[k];
    __syncthreads();

    // ---- phase 2: q = h @ W_hid + b_hid ----
    {
        int j = tid;
        float acc = bhid[j];
        for (int k = 0; k < HH; k += 4) {
            float4 hv = *reinterpret_cast<const float4*>(&hsh[k]);
            acc = fmaf(hv.x, Whid[(k+0)*HH+j], acc);
            acc = fmaf(hv.y, Whid[(k+1)*HH+j], acc);
            acc = fmaf(hv.z, Whid[(k+2)*HH+j], acc);
            acc = fmaf(hv.w, Whid[(k+3)*HH+j], acc);
        }
        qs[j] = acc;
    }
    __syncthreads();

    // ---- phase 3: scores[a] = tanh(q + mem[a]) . v_w + v_b (masked) ----
    {
        int w = tid >> 6, lane = tid & 63;
        for (int r = 0; r < 4; r++) {
            int a = w + 8*r;
            const float* mem = hs + ((size_t)b*HSROW + (t + a))*HH;
            float p = 0.f;
            for (int j = lane; j < HH; j += 64) p += tanhf(qs[j] + mem[j]) * vw[j];
            for (int m = 32; m >= 1; m >>= 1) p += __shfl_xor(p, m);
            if (lane == 0) sc[a] = (a >= AA - t) ? (p + vb[0]) : -1e20f;
        }
    }
    __syncthreads();

    // ---- phase 4: softmax over 32 (wave 0) ----
    if (tid < 64) {
        float v = (tid < 32) ? sc[tid] : -FLTMAX;
        float m = v;
        for (int sh = 16; sh >= 1; sh >>= 1) m = fmaxf(m, __shfl_xor(m, sh));
        float e = (tid < 32) ? __expf(v - m) : 0.f;
        float ss = e;
        for (int sh = 16; sh >= 1; sh >>= 1) ss += __shfl_xor(ss, sh);
        if (tid < 32) at[tid] = e / ss;
    }
    __syncthreads();

    // ---- phase 5: context ----
    {
        int j = tid;
        float ctx = 0.f;
        for (int a = 0; a < AA; a++)
            ctx += at[a] * hs[((size_t)b*HSROW + (t + a))*HH + j];
        ctxs[j] = ctx;
    }
    __syncthreads();

    // ---- phase 6: hid = selu(xwpre + context @ W_ctx[512:1024]) ----
    {
        int j = tid;
        float acc = xwpre[((size_t)t*BB + b)*HH + j];
        const float* W2 = Wctx + (size_t)HH*HH;
        for (int k = 0; k < HH; k += 4) {
            float4 hv = *reinterpret_cast<const float4*>(&ctxs[k]);
            acc = fmaf(hv.x, W2[(k+0)*HH+j], acc);
            acc = fmaf(hv.y, W2[(k+1)*HH+j], acc);
            acc = fmaf(hv.z, W2[(k+2)*HH+j], acc);
            acc = fmaf(hv.w, W2[(k+3)*HH+j], acc);
        }
        const float scl = 1.0507009873554805f, al = 1.6732632423543772f;
        hidg[b*HH + j] = (acc > 0.f) ? scl*acc : scl*al*expm1f(acc);
    }
}

// ---------------- per-step kernel 2: gates + h_new/c_new + hs_buf write ----------------
__global__ __launch_bounds__(256) void k_gates(
    int t, const float* __restrict__ Wih, const float* __restrict__ Whh,
    const float* __restrict__ blstm, const float* __restrict__ wsw,
    const float* __restrict__ hidg, float* __restrict__ hs,
    float* __restrict__ cvec, float* __restrict__ spart)
{
    int bid = blockIdx.x, b = bid >> 3, hc = bid & 7, h0 = hc*64;
    int tid = threadIdx.x, g = tid >> 6, jj = tid & 63, j = h0 + jj, col = g*HH + j;
    __shared__ float hid_s[HH], h_s[HH];
    __shared__ float gsl[4][64];
    const float* hp = hs + ((size_t)b*HSROW + (AA + t - 1))*HH;
    for (int k = tid; k < HH; k += 256) { hid_s[k] = hidg[b*HH + k]; h_s[k] = hp[k]; }
    __syncthreads();
    float acc = blstm[col];
    for (int k = 0; k < HH; k += 4) {
        float4 hv = *reinterpret_cast<const float4*>(&hid_s[k]);
        acc = fmaf(hv.x, Wih[(size_t)(k+0)*2048 + col], acc);
        acc = fmaf(hv.y, Wih[(size_t)(k+1)*2048 + col], acc);
        acc = fmaf(hv.z, Wih[(size_t)(k+2)*2048 + col], acc);
        acc = fmaf(hv.w, Wih[(size_t)(k+3)*2048 + col], acc);
    }
    for (int k = 0; k < HH; k += 4) {
        float4 hv = *reinterpret_cast<const float4*>(&h_s[k]);
        acc = fmaf(hv.x, Whh[(size_t)(k+0)*2048 + col], acc);
        acc = fmaf(hv.y, Whh[(size_t)(k+1)*2048 + col], acc);
        acc = fmaf(hv.z, Whh[(size_t)(k+2)*2048 + col], acc);
        acc = fmaf(hv.w, Whh[(size_t)(k+3)*2048 + col], acc);
    }
    gsl[g][jj] = acc;
    __syncthreads();
    if (tid < 64) {
        float gi = gsl[0][jj], gf = gsl[1][jj], gg = gsl[2][jj], go = gsl[3][jj];
        float cp = cvec[b*HH + j];
        float cn = sigm(gf)*cp + sigm(gi)*tanhf(gg);
        float hn = sigm(go)*tanhf(cn);
        cvec[b*HH + j] = cn;
        hs[((size_t)b*HSROW + (AA + t))*HH + j] = hn;
        float sp = hn*wsw[j] + cn*wsw[HH + j];
        for (int m = 32; m >= 1; m >>= 1) sp += __shfl_xor(sp, m);
        if (jj == 0) spart[b*8 + hc] = sp;
    }
}

// ---------------- per-step kernel 3: logits chunk -> store logits + per-block max ----------------
__global__ __launch_bounds__(256) void k_logits(
    int t, const int* __restrict__ parents,
    const float* __restrict__ Wg, const float* __restrict__ bg,
    const float* __restrict__ hs, const float* __restrict__ cvec,
    float* __restrict__ lb, float* __restrict__ pmax)
{
    int bid = blockIdx.x, tid = threadIdx.x;
    int c0 = bid * CHW, cl = tid & 127, kh = tid >> 7;
    int col = c0 + cl;
    int par = parents[t];
    int tm1 = (t - 1 > 0) ? (t - 1) : 0;
    int p = (par < 0) ? 0 : ((par > tm1) ? tm1 : par);

    __shared__ float zs[BB][HH];      // staged z chunk (k-chunk of 512)
    __shared__ float red[BB][CHW];
    __shared__ float bmx[2][BB];
    float acc[BB];
    #pragma unroll
    for (int b2 = 0; b2 < BB; b2++) acc[b2] = (kh == 0) ? bg[col] : 0.f;

    for (int kc = 0; kc < 3; kc++) {
        // stage z = [h_new | c_new | h_par]
        for (int i = tid; i < BB*HH; i += 256) {
            int b2 = i >> 9, k = i & 511, kg = kc*512 + k;
            float v;
            if (kg < HH)            v = hs[((size_t)b2*HSROW + (AA + t))*HH + kg];
            else if (kg < 2*HH)     v = cvec[b2*HH + (kg - HH)];
            else                    v = (t == 0) ? 0.f
                                        : hs[((size_t)b2*HSROW + (AA + p))*HH + (kg - 2*HH)];
            zs[b2][k] = v;
        }
        __syncthreads();
        const float* wbase = Wg + (size_t)(kc*512)*VV + col;
        for (int k4 = 0; k4 < 64; k4++) {
            int kb = kh*256 + k4*4;
            const float* wr = wbase + (size_t)kb*VV;
            float w0 = wr[0], w1 = wr[VV], w2 = wr[2*VV], w3 = wr[3*VV];
            #pragma unroll
            for (int b2 = 0; b2 < BB; b2++) {
                float4 z = *reinterpret_cast<const float4*>(&zs[b2][kb]);
                acc[b2] = fmaf(z.x, w0, fmaf(z.y, w1, fmaf(z.z, w2, fmaf(z.w, w3, acc[b2]))));
            }
        }
        __syncthreads();
    }

    // combine the two k-halves
    if (kh == 1) { for (int b2 = 0; b2 < BB; b2++) red[b2][cl] = acc[b2]; }
    __syncthreads();
    int wv = tid >> 6, lane = tid & 63;
    if (kh == 0) {
        #pragma unroll
        for (int b2 = 0; b2 < BB; b2++) acc[b2] += red[b2][cl];
        // store logits (fp32, exact values the finisher will re-quantize)
        #pragma unroll
        for (int b2 = 0; b2 < BB; b2++) lb[(size_t)b2*VV + col] = acc[b2];
        // per-block max per b
        for (int b2 = 0; b2 < BB; b2++) {
            float v = acc[b2];
            for (int m = 32; m >= 1; m >>= 1) v = fmaxf(v, __shfl_xor(v, m));
            if (lane == 0) bmx[wv][b2] = v;
        }
    }
    __syncthreads();
    if (tid < BB) pmax[bid*BB + tid] = fmaxf(bmx[0][tid], bmx[1][tid]);
}

// ---------------- finish last step (tp = TT-1), 16 blocks ----------------
__global__ __launch_bounds__(512) void k_fin_last(
    const int* __restrict__ s,
    const float* __restrict__ lb, const float* __restrict__ pmax,
    const float* __restrict__ spart, const float* __restrict__ bsw,
    float* __restrict__ nll, float* __restrict__ out)
{
    __shared__ float cv[512];
    __shared__ int   ci[512];
    __shared__ double sdd[512];
    __shared__ float extra[2];
    finish_step(TT-1, blockIdx.x, threadIdx.x, s, lb, pmax, spart, bsw, nll, out, cv, ci, sdd, extra);
}

// ---------------- loss ----------------
__global__ __launch_bounds__(256) void k_final_loss(
    const float* __restrict__ nll, float* __restrict__ out)
{
    __shared__ double cs2[256];
    int tid = threadIdx.x;
    double psm = 0.0;
    for (int i = tid; i < TT*BB; i += 256) psm += (double)nll[i];
    cs2[tid] = psm; __syncthreads();
    for (int sft = 128; sft >= 1; sft >>= 1) {
        if (tid < sft) cs2[tid] += cs2[tid+sft];
        __syncthreads();
    }
    if (tid == 0) out[0] = (float)(cs2[0] / (double)BB);
}

extern "C" void kernel_launch(void* const* d_in, const int* in_sizes, int n_in,
                              void* d_out, int out_size, void* d_ws, size_t ws_size,
                              hipStream_t stream)
{
    const int*   s_tok = (const int*)  d_in[0];
    const int*   par   = (const int*)  d_in[1];
    const float* emb   = (const float*)d_in[2];
    const float* Whid  = (const float*)d_in[3];
    const float* bhid  = (const float*)d_in[4];
    const float* vw    = (const float*)d_in[5];
    const float* vb    = (const float*)d_in[6];
    const float* Wctx  = (const float*)d_in[7];
    const float* bctx  = (const float*)d_in[8];
    const float* Wih   = (const float*)d_in[9];
    const float* Whh   = (const float*)d_in[10];
    const float* blstm = (const float*)d_in[11];
    const float* Wg    = (const float*)d_in[12];
    const float* bg    = (const float*)d_in[13];
    const float* wsw   = (const float*)d_in[14];
    const float* bsw   = (const float*)d_in[15];
    float* out = (float*)d_out;

    float* ws    = (float*)d_ws;
    float* hs    = ws;                     // 16*96*512 = 786432
    float* cvec  = hs    + 786432;         // 8192
    float* xwpre = cvec  + 8192;           // 63*16*512 = 516096
    float* hidg  = xwpre + 516096;         // 8192
    float* pmax  = hidg  + 8192;           // 4000
    float* spart = pmax  + 4000;           // 128
    float* nll   = spart + 128;            // 1008
    float* lb    = nll   + 1008;           // 16*32000 = 512000

    // zero hs_buf + cvec (adjacent)
    hipMemsetAsync(hs, 0, (786432 + 8192) * sizeof(float), stream);

    hipLaunchKernelGGL(k_pre, dim3(TT*BB), dim3(256), 0, stream, s_tok, emb, Wctx, bctx, xwpre);

    for (int t = 0; t < TT; t++) {
        hipLaunchKernelGGL(k_attn, dim3(BB), dim3(512), 0, stream,
            t, s_tok, Whid, bhid, vw, vb, Wctx, xwpre, hs, hidg,
            lb, pmax, spart, bsw, nll, out);
        hipLaunchKernelGGL(k_gates, dim3(128), dim3(256), 0, stream,
            t, Wih, Whh, blstm, wsw, hidg, hs, cvec, spart);
        hipLaunchKernelGGL(k_logits, dim3(NCHUNK), dim3(256), 0, stream,
            t, par, Wg, bg, hs, cvec, lb, pmax);
    }

    hipLaunchKernelGGL(k_fin_last, dim3(BB), dim3(512), 0, stream,
        s_tok, lb, pmax, spart, bsw, nll, out);
    hipLaunchKernelGGL(k_final_loss, dim3(1), dim3(256), 0, stream, nll, out);
}

// Round 3
// 13222.845 us; speedup vs baseline: 1.0781x; 1.0781x over previous
//
#include <hip/hip_runtime.h>
#include <math.h>

#define BB 16
#define LL 64
#define TT 63          // L-1 steps
#define HH 512
#define AA 32          // ATTN window
#define VV 32000
#define NCHUNK 250     // V chunks for big matmul
#define CHW 128        // cols per chunk (250*128 = 32000)
#define PAD_TOK 1
#define SOS_TOK 2
#define HSROW 96       // A + L rows in hs_buf
#define FLTMAX 3.402823466e38f

__device__ __forceinline__ float sigm(float x){ return 1.0f/(1.0f + __expf(-x)); }

// ---------------- prologue: xwpre[t][b][:] = b_ctx + emb[tok(t,b)] @ W_ctx[0:512] ----------------
// 504 blocks = 63 t * 8 j-chunks; each block reads its W_ctx column slice ONCE for all 16 b.
// Per-(t,b,j) fmaf chain identical to the round-2 version (k = 0..511 in fours, same order).
__global__ __launch_bounds__(256) void k_pre(const int* __restrict__ s, const float* __restrict__ emb,
                      const float* __restrict__ Wctx, const float* __restrict__ bctx,
                      float* __restrict__ xwpre)
{
    int t = blockIdx.x >> 3;          // 0..62
    int jc = blockIdx.x & 7;          // 0..7
    int tid = threadIdx.x;
    int jj = tid & 63, bq = tid >> 6; // bq 0..3
    int j = jc*64 + jj;
    __shared__ int toks[BB];
    __shared__ float xs[BB][HH];
    if (tid < BB) {
        int b = tid;
        toks[b] = (t == 0) ? SOS_TOK : s[b*LL + (t-1)];
    }
    __syncthreads();
    for (int i = tid; i < BB*HH; i += 256) {
        int b = i >> 9, k = i & 511;
        xs[b][k] = emb[(size_t)toks[b]*HH + k];
    }
    __syncthreads();
    float acc[4];
    #pragma unroll
    for (int u = 0; u < 4; u++) acc[u] = bctx[j];
    for (int k = 0; k < HH; k += 4) {
        float w0 = Wctx[(k+0)*HH+j], w1 = Wctx[(k+1)*HH+j],
              w2 = Wctx[(k+2)*HH+j], w3 = Wctx[(k+3)*HH+j];
        #pragma unroll
        for (int u = 0; u < 4; u++) {
            int b = bq*4 + u;
            float4 hv = *reinterpret_cast<const float4*>(&xs[b][k]);
            acc[u] = fmaf(hv.x, w0, acc[u]);
            acc[u] = fmaf(hv.y, w1, acc[u]);
            acc[u] = fmaf(hv.z, w2, acc[u]);
            acc[u] = fmaf(hv.w, w3, acc[u]);
        }
    }
    #pragma unroll
    for (int u = 0; u < 4; u++) {
        int b = bq*4 + u;
        xwpre[((size_t)t*BB + b)*HH + j] = acc[u];
    }
}

// ---------------- step-finish: replicate fp32 log_softmax + s*logp quantization ----------------
// (bit-identical to round 2)
__device__ void finish_step(int tp, int b, int tid,
                            const int* __restrict__ s,
                            const float* __restrict__ lb,
                            const float* __restrict__ pmax,
                            const float* __restrict__ spart,
                            const float* __restrict__ bsw,
                            float* __restrict__ nll, float* __restrict__ out,
                            float* cv, int* ci, double* sdd, float* extra)
{
    // gmax over 250 chunk maxes
    float v = -FLTMAX;
    if (tid < NCHUNK) v = pmax[tid*BB + b];
    cv[tid] = v; __syncthreads();
    for (int sft = 256; sft >= 1; sft >>= 1) {
        if (tid < sft) cv[tid] = fmaxf(cv[tid], cv[tid+sft]);
        __syncthreads();
    }
    float gmax = cv[0];
    __syncthreads();

    // pass A: S = sum exp(fl32(x - gmax)), fp64 Taylor (|u| small; bias-free)
    const float* Lb = lb + (size_t)b*VV;
    double sd = 0.0;
    for (int col = tid; col < VV; col += 512) {
        float d1 = Lb[col] - gmax;
        double u = (double)d1, e;
        if (u < -0.25) {
            e = exp(u);
        } else {
            e = 1.0 + u*(1.0/7.0);
            e = 1.0 + u*e*(1.0/6.0);
            e = 1.0 + u*e*(1.0/5.0);
            e = 1.0 + u*e*(1.0/4.0);
            e = 1.0 + u*e*(1.0/3.0);
            e = 1.0 + u*e*(1.0/2.0);
            e = 1.0 + u*e;
        }
        sd += e;
    }
    sdd[tid] = sd; __syncthreads();
    for (int sft = 256; sft >= 1; sft >>= 1) {
        if (tid < sft) sdd[tid] += sdd[tid+sft];
        __syncthreads();
    }
    float logS = logf((float)sdd[0]);

    // switch s = sigmoid(z), precise expf (replicates np's 1/(1+exp(-z)))
    float z = bsw[0];
    #pragma unroll
    for (int i2 = 0; i2 < 8; i2++) z += spart[b*8 + i2];
    float sF = 1.0f/(1.0f + expf(-z));
    __syncthreads();

    // pass B: quantized argmax + target capture
    int tg = s[b*LL + tp + 1];
    float best = -FLTMAX; int bidx = 0x7fffffff;
    for (int col = tid; col < VV; col += 512) {
        float d1 = Lb[col] - gmax;
        float d2 = d1 - logS;
        float pq = sF * d2;
        if (pq > best) { best = pq; bidx = col; }
        if (col == tg) extra[0] = pq;
    }
    cv[tid] = best; ci[tid] = bidx; __syncthreads();
    for (int sft = 256; sft >= 1; sft >>= 1) {
        if (tid < sft) {
            float v2 = cv[tid+sft]; int i2 = ci[tid+sft];
            if (v2 > cv[tid] || (v2 == cv[tid] && i2 < ci[tid])) { cv[tid] = v2; ci[tid] = i2; }
        }
        __syncthreads();
    }
    if (tid == 0) {
        out[1 + b*TT + tp] = (float)ci[0];
        nll[tp*BB + b] = (tg != PAD_TOK) ? -extra[0] : 0.f;
    }
    __syncthreads();
}

// ---------------- per-step kernel 1: finish prev step + attention + hid ----------------
// (bit-identical to round 2)
__global__ __launch_bounds__(512) void k_attn(
    int t, const int* __restrict__ s,
    const float* __restrict__ Whid, const float* __restrict__ bhid,
    const float* __restrict__ vw, const float* __restrict__ vb,
    const float* __restrict__ Wctx, const float* __restrict__ xwpre,
    const float* __restrict__ hs, float* __restrict__ hidg,
    const float* __restrict__ lb, const float* __restrict__ pmax,
    const float* __restrict__ spart, const float* __restrict__ bsw,
    float* __restrict__ nll, float* __restrict__ out)
{
    int b = blockIdx.x, tid = threadIdx.x;
    __shared__ float hsh[HH], qs[HH], ctxs[HH];
    __shared__ float sc[AA], at[AA];
    __shared__ float cv[512];
    __shared__ int   ci[512];
    __shared__ double sdd[512];
    __shared__ float extra[2];

    // ---- phase 0: finish step t-1 ----
    if (t > 0) {
        finish_step(t-1, b, tid, s, lb, pmax, spart, bsw, nll, out, cv, ci, sdd, extra);
    }

    // ---- phase 1: load h_prev (hs row A+t-1; t=0 -> row 31 = zeros) ----
    const float* hp = hs + ((size_t)b*HSROW + (AA + t - 1))*HH;
    for (int k = tid; k < HH; k += 512) hsh[k] = hp[k];
    __syncthreads();

    // ---- phase 2: q = h @ W_hid + b_hid ----
    {
        int j = tid;
        float acc = bhid[j];
        for (int k = 0; k < HH; k += 4) {
            float4 hv = *reinterpret_cast<const float4*>(&hsh[k]);
            acc = fmaf(hv.x, Whid[(k+0)*HH+j], acc);
            acc = fmaf(hv.y, Whid[(k+1)*HH+j], acc);
            acc = fmaf(hv.z, Whid[(k+2)*HH+j], acc);
            acc = fmaf(hv.w, Whid[(k+3)*HH+j], acc);
        }
        qs[j] = acc;
    }
    __syncthreads();

    // ---- phase 3: scores[a] = tanh(q + mem[a]) . v_w + v_b (masked) ----
    {
        int w = tid >> 6, lane = tid & 63;
        for (int r = 0; r < 4; r++) {
            int a = w + 8*r;
            const float* mem = hs + ((size_t)b*HSROW + (t + a))*HH;
            float p = 0.f;
            for (int j = lane; j < HH; j += 64) p += tanhf(qs[j] + mem[j]) * vw[j];
            for (int m = 32; m >= 1; m >>= 1) p += __shfl_xor(p, m);
            if (lane == 0) sc[a] = (a >= AA - t) ? (p + vb[0]) : -1e20f;
        }
    }
    __syncthreads();

    // ---- phase 4: softmax over 32 (wave 0) ----
    if (tid < 64) {
        float v = (tid < 32) ? sc[tid] : -FLTMAX;
        float m = v;
        for (int sh = 16; sh >= 1; sh >>= 1) m = fmaxf(m, __shfl_xor(m, sh));
        float e = (tid < 32) ? __expf(v - m) : 0.f;
        float ss = e;
        for (int sh = 16; sh >= 1; sh >>= 1) ss += __shfl_xor(ss, sh);
        if (tid < 32) at[tid] = e / ss;
    }
    __syncthreads();

    // ---- phase 5: context ----
    {
        int j = tid;
        float ctx = 0.f;
        for (int a = 0; a < AA; a++)
            ctx += at[a] * hs[((size_t)b*HSROW + (t + a))*HH + j];
        ctxs[j] = ctx;
    }
    __syncthreads();

    // ---- phase 6: hid = selu(xwpre + context @ W_ctx[512:1024]) ----
    {
        int j = tid;
        float acc = xwpre[((size_t)t*BB + b)*HH + j];
        const float* W2 = Wctx + (size_t)HH*HH;
        for (int k = 0; k < HH; k += 4) {
            float4 hv = *reinterpret_cast<const float4*>(&ctxs[k]);
            acc = fmaf(hv.x, W2[(k+0)*HH+j], acc);
            acc = fmaf(hv.y, W2[(k+1)*HH+j], acc);
            acc = fmaf(hv.z, W2[(k+2)*HH+j], acc);
            acc = fmaf(hv.w, W2[(k+3)*HH+j], acc);
        }
        const float scl = 1.0507009873554805f, al = 1.6732632423543772f;
        hidg[b*HH + j] = (acc > 0.f) ? scl*acc : scl*al*expm1f(acc);
    }
}

// ---------------- per-step kernel 2: gates + h_new/c_new + hs_buf write ----------------
// (bit-identical to round 2)
__global__ __launch_bounds__(256) void k_gates(
    int t, const float* __restrict__ Wih, const float* __restrict__ Whh,
    const float* __restrict__ blstm, const float* __restrict__ wsw,
    const float* __restrict__ hidg, float* __restrict__ hs,
    float* __restrict__ cvec, float* __restrict__ spart)
{
    int bid = blockIdx.x, b = bid >> 3, hc = bid & 7, h0 = hc*64;
    int tid = threadIdx.x, g = tid >> 6, jj = tid & 63, j = h0 + jj, col = g*HH + j;
    __shared__ float hid_s[HH], h_s[HH];
    __shared__ float gsl[4][64];
    const float* hp = hs + ((size_t)b*HSROW + (AA + t - 1))*HH;
    for (int k = tid; k < HH; k += 256) { hid_s[k] = hidg[b*HH + k]; h_s[k] = hp[k]; }
    __syncthreads();
    float acc = blstm[col];
    for (int k = 0; k < HH; k += 4) {
        float4 hv = *reinterpret_cast<const float4*>(&hid_s[k]);
        acc = fmaf(hv.x, Wih[(size_t)(k+0)*2048 + col], acc);
        acc = fmaf(hv.y, Wih[(size_t)(k+1)*2048 + col], acc);
        acc = fmaf(hv.z, Wih[(size_t)(k+2)*2048 + col], acc);
        acc = fmaf(hv.w, Wih[(size_t)(k+3)*2048 + col], acc);
    }
    for (int k = 0; k < HH; k += 4) {
        float4 hv = *reinterpret_cast<const float4*>(&h_s[k]);
        acc = fmaf(hv.x, Whh[(size_t)(k+0)*2048 + col], acc);
        acc = fmaf(hv.y, Whh[(size_t)(k+1)*2048 + col], acc);
        acc = fmaf(hv.z, Whh[(size_t)(k+2)*2048 + col], acc);
        acc = fmaf(hv.w, Whh[(size_t)(k+3)*2048 + col], acc);
    }
    gsl[g][jj] = acc;
    __syncthreads();
    if (tid < 64) {
        float gi = gsl[0][jj], gf = gsl[1][jj], gg = gsl[2][jj], go = gsl[3][jj];
        float cp = cvec[b*HH + j];
        float cn = sigm(gf)*cp + sigm(gi)*tanhf(gg);
        float hn = sigm(go)*tanhf(cn);
        cvec[b*HH + j] = cn;
        hs[((size_t)b*HSROW + (AA + t))*HH + j] = hn;
        float sp = hn*wsw[j] + cn*wsw[HH + j];
        for (int m = 32; m >= 1; m >>= 1) sp += __shfl_xor(sp, m);
        if (jj == 0) spart[b*8 + hc] = sp;
    }
}

// ---------------- per-step kernel 3: logits chunk -> store logits + per-block max ----------------
// 250 blocks x 512 threads: 128 cols x 2 kh x 2 batch-halves (8 acc chains per thread).
// Every (col,b2,kh) fmaf chain and the kh0+kh1 combine are bit-identical to round 2;
// only the thread assignment changed (2x waves, 4x shorter per-thread serial work).
__global__ __launch_bounds__(512) void k_logits(
    int t, const int* __restrict__ parents,
    const float* __restrict__ Wg, const float* __restrict__ bg,
    const float* __restrict__ hs, const float* __restrict__ cvec,
    float* __restrict__ lb, float* __restrict__ pmax)
{
    int bid = blockIdx.x, tid = threadIdx.x;
    int cl = tid & 127, kh = (tid >> 7) & 1, bh = tid >> 8;
    int col = bid * CHW + cl;
    int b0 = bh * 8;
    int par = parents[t];
    int tm1 = (t - 1 > 0) ? (t - 1) : 0;
    int p = (par < 0) ? 0 : ((par > tm1) ? tm1 : par);

    __shared__ float zs[BB][HH];      // staged z chunk (k-chunk of 512)
    __shared__ float red[BB][CHW];
    __shared__ float bmx[2][BB];
    float acc[8];
    #pragma unroll
    for (int u = 0; u < 8; u++) acc[u] = (kh == 0) ? bg[col] : 0.f;

    for (int kc = 0; kc < 3; kc++) {
        // stage z = [h_new | c_new | h_par]
        for (int i = tid; i < BB*HH; i += 512) {
            int b2 = i >> 9, k = i & 511, kg = kc*512 + k;
            float v;
            if (kg < HH)            v = hs[((size_t)b2*HSROW + (AA + t))*HH + kg];
            else if (kg < 2*HH)     v = cvec[b2*HH + (kg - HH)];
            else                    v = (t == 0) ? 0.f
                                        : hs[((size_t)b2*HSROW + (AA + p))*HH + (kg - 2*HH)];
            zs[b2][k] = v;
        }
        __syncthreads();
        const float* wbase = Wg + (size_t)(kc*512)*VV + col;
        #pragma unroll 4
        for (int k4 = 0; k4 < 64; k4++) {
            int kb = kh*256 + k4*4;
            const float* wr = wbase + (size_t)kb*VV;
            float w0 = wr[0], w1 = wr[VV], w2 = wr[2*VV], w3 = wr[3*VV];
            #pragma unroll
            for (int u = 0; u < 8; u++) {
                float4 z = *reinterpret_cast<const float4*>(&zs[b0 + u][kb]);
                acc[u] = fmaf(z.x, w0, fmaf(z.y, w1, fmaf(z.z, w2, fmaf(z.w, w3, acc[u]))));
            }
        }
        __syncthreads();
    }

    // combine the two k-halves (same accA + accB order as round 2)
    if (kh == 1) {
        #pragma unroll
        for (int u = 0; u < 8; u++) red[b0 + u][cl] = acc[u];
    }
    __syncthreads();
    int lane = tid & 63;
    int half = cl >> 6;               // 0: cols 0-63, 1: cols 64-127
    if (kh == 0) {
        #pragma unroll
        for (int u = 0; u < 8; u++) {
            acc[u] += red[b0 + u][cl];
            lb[(size_t)(b0 + u)*VV + col] = acc[u];
        }
        #pragma unroll
        for (int u = 0; u < 8; u++) {
            float v = acc[u];
            for (int m = 32; m >= 1; m >>= 1) v = fmaxf(v, __shfl_xor(v, m));
            if (lane == 0) bmx[half][b0 + u] = v;
        }
    }
    __syncthreads();
    if (tid < BB) pmax[bid*BB + tid] = fmaxf(bmx[0][tid], bmx[1][tid]);
}

// ---------------- finish last step (tp = TT-1), 16 blocks ----------------
__global__ __launch_bounds__(512) void k_fin_last(
    const int* __restrict__ s,
    const float* __restrict__ lb, const float* __restrict__ pmax,
    const float* __restrict__ spart, const float* __restrict__ bsw,
    float* __restrict__ nll, float* __restrict__ out)
{
    __shared__ float cv[512];
    __shared__ int   ci[512];
    __shared__ double sdd[512];
    __shared__ float extra[2];
    finish_step(TT-1, blockIdx.x, threadIdx.x, s, lb, pmax, spart, bsw, nll, out, cv, ci, sdd, extra);
}

// ---------------- loss ----------------
__global__ __launch_bounds__(256) void k_final_loss(
    const float* __restrict__ nll, float* __restrict__ out)
{
    __shared__ double cs2[256];
    int tid = threadIdx.x;
    double psm = 0.0;
    for (int i = tid; i < TT*BB; i += 256) psm += (double)nll[i];
    cs2[tid] = psm; __syncthreads();
    for (int sft = 128; sft >= 1; sft >>= 1) {
        if (tid < sft) cs2[tid] += cs2[tid+sft];
        __syncthreads();
    }
    if (tid == 0) out[0] = (float)(cs2[0] / (double)BB);
}

extern "C" void kernel_launch(void* const* d_in, const int* in_sizes, int n_in,
                              void* d_out, int out_size, void* d_ws, size_t ws_size,
                              hipStream_t stream)
{
    const int*   s_tok = (const int*)  d_in[0];
    const int*   par   = (const int*)  d_in[1];
    const float* emb   = (const float*)d_in[2];
    const float* Whid  = (const float*)d_in[3];
    const float* bhid  = (const float*)d_in[4];
    const float* vw    = (const float*)d_in[5];
    const float* vb    = (const float*)d_in[6];
    const float* Wctx  = (const float*)d_in[7];
    const float* bctx  = (const float*)d_in[8];
    const float* Wih   = (const float*)d_in[9];
    const float* Whh   = (const float*)d_in[10];
    const float* blstm = (const float*)d_in[11];
    const float* Wg    = (const float*)d_in[12];
    const float* bg    = (const float*)d_in[13];
    const float* wsw   = (const float*)d_in[14];
    const float* bsw   = (const float*)d_in[15];
    float* out = (float*)d_out;

    float* ws    = (float*)d_ws;
    float* hs    = ws;                     // 16*96*512 = 786432
    float* cvec  = hs    + 786432;         // 8192
    float* xwpre = cvec  + 8192;           // 63*16*512 = 516096
    float* hidg  = xwpre + 516096;         // 8192
    float* pmax  = hidg  + 8192;           // 4000
    float* spart = pmax  + 4000;           // 128
    float* nll   = spart + 128;            // 1008
    float* lb    = nll   + 1008;           // 16*32000 = 512000

    // zero hs_buf + cvec (adjacent)
    hipMemsetAsync(hs, 0, (786432 + 8192) * sizeof(float), stream);

    hipLaunchKernelGGL(k_pre, dim3(TT*8), dim3(256), 0, stream, s_tok, emb, Wctx, bctx, xwpre);

    for (int t = 0; t < TT; t++) {
        hipLaunchKernelGGL(k_attn, dim3(BB), dim3(512), 0, stream,
            t, s_tok, Whid, bhid, vw, vb, Wctx, xwpre, hs, hidg,
            lb, pmax, spart, bsw, nll, out);
        hipLaunchKernelGGL(k_gates, dim3(128), dim3(256), 0, stream,
            t, Wih, Whh, blstm, wsw, hidg, hs, cvec, spart);
        hipLaunchKernelGGL(k_logits, dim3(NCHUNK), dim3(512), 0, stream,
            t, par, Wg, bg, hs, cvec, lb, pmax);
    }

    hipLaunchKernelGGL(k_fin_last, dim3(BB), dim3(512), 0, stream,
        s_tok, lb, pmax, spart, bsw, nll, out);
    hipLaunchKernelGGL(k_final_loss, dim3(1), dim3(256), 0, stream, nll, out);
}